// Round 19
// baseline (999.302 us; speedup 1.0000x reference)
//
#include <hip/hip_runtime.h>

typedef __attribute__((ext_vector_type(8))) short bf16x8;
typedef __attribute__((ext_vector_type(4))) float f32x4;
typedef __attribute__((ext_vector_type(4))) int i32x4;
typedef __attribute__((ext_vector_type(2))) int i32x2;

#define B_ 4
#define N_ 65536
#define RRR_ 32768
#define PADV_ 39304   // 34^3
#define PPLANE_ 1156  // 34*34

// ---- workspace layout (float offsets) ----
static const size_t OFF_NC     = 0;         //  [4][3][65536] f32
static const size_t OFF_VIDX   = 786432;    //  [4][65536] int
static const size_t OFF_WT1    = 1048576;   //  [2ch][27][128][32] bf16 PLAIN
static const size_t OFF_WT2    = 1159168;   //  [4ch][27][128][32] bf16 PLAIN
static const size_t OFF_C2OUT  = 1380352;   //  [4][32768][128] bf16
static const size_t OFF_CNT    = 9768960;   //  [4][32768] f32        (memset)
static const size_t OFF_GSUM   = 9900032;   //  [4][32768][64] f32    (memset)
static const size_t OFF_GPAD   = 18288640;  //  [4][39304][64] bf16   (halo-zeroed)
static const size_t OFF_ACT1   = 23319552;  //  [4][39304][128] bf16  (halo-zeroed)
static const size_t OFF_GSTATS = 33381376;  //  [3][4][8][2] f32 raw sum/ssq (memset)
static const size_t OFF_BSTATS = 33381568;  //  [4][4] f32 (sum x3, maxbits) (memset)
static const size_t MEMSET1_FLOATS = 131072 + 8388608;   // cnt + gsum
// pbf [4][128][65536] bf16 reuses gsum/gpad/act1 (all dead after conv2)
static const size_t OFF_PBF    = 9900032;

__device__ __forceinline__ ushort f2bf(float x) {
    union { float f; unsigned u; } c; c.f = x;
    unsigned r = c.u + 0x7fffu + ((c.u >> 16) & 1u);
    return (ushort)(r >> 16);
}
__device__ __forceinline__ float bf2f(ushort h) {
    union { unsigned u; float f; } c; c.u = ((unsigned)h) << 16;
    return c.f;
}

__device__ __forceinline__ void gl16(const void* g, void* l) {
    __builtin_amdgcn_global_load_lds(
        (const __attribute__((address_space(1))) unsigned int*)(g),
        (__attribute__((address_space(3))) unsigned int*)(l),
        16, 0, 0);
}

// ---------------- zero only the halo cells of a padded channels-last buffer ----------------
template <int CH8>
__global__ __launch_bounds__(256) void k_zero_halo(ushort* __restrict__ buf) {
    int idx = blockIdx.x * 256 + threadIdx.x;       // B * PADV * CH8
    if (idx >= B_ * PADV_ * CH8) return;
    int c8 = idx % CH8;
    int t = idx / CH8;
    int vox = t % PADV_;
    int b = t / PADV_;
    int z = vox / PPLANE_;
    int rem = vox - z * PPLANE_;
    int y = rem / 34;
    int x = rem - y * 34;
    if (z == 0 || z == 33 || y == 0 || y == 33 || x == 0 || x == 33) {
        i32x4 zero = (i32x4){0, 0, 0, 0};
        *(i32x4*)(buf + ((size_t)b * PADV_ + vox) * (CH8 * 8) + c8 * 8) = zero;
    }
}

// ---------------- coord partial sums ----------------
__global__ __launch_bounds__(256) void k_coord_sum(const float* __restrict__ coords,
                                                   float* __restrict__ bstats) {
    int b = blockIdx.y;
    int tid = threadIdx.x;
    const float* cb = coords + (size_t)b * 3 * N_;
    float s0 = 0.f, s1 = 0.f, s2 = 0.f;
    for (int n = blockIdx.x * 256 + tid; n < N_; n += 64 * 256) {
        s0 += cb[n]; s1 += cb[N_ + n]; s2 += cb[2 * N_ + n];
    }
    #pragma unroll
    for (int off = 1; off < 64; off <<= 1) {
        s0 += __shfl_xor(s0, off);
        s1 += __shfl_xor(s1, off);
        s2 += __shfl_xor(s2, off);
    }
    if ((tid & 63) == 0) {
        atomicAdd(&bstats[b * 4 + 0], s0);
        atomicAdd(&bstats[b * 4 + 1], s1);
        atomicAdd(&bstats[b * 4 + 2], s2);
    }
}

// ---------------- coord max-norm (after sums) ----------------
__global__ __launch_bounds__(256) void k_coord_max(const float* __restrict__ coords,
                                                   float* __restrict__ bstats) {
    int b = blockIdx.y;
    int tid = threadIdx.x;
    const float invN = 1.0f / (float)N_;
    float m0 = bstats[b * 4 + 0] * invN;
    float m1 = bstats[b * 4 + 1] * invN;
    float m2 = bstats[b * 4 + 2] * invN;
    const float* cb = coords + (size_t)b * 3 * N_;
    float mx = 0.f;
    for (int n = blockIdx.x * 256 + tid; n < N_; n += 64 * 256) {
        float x = cb[n] - m0, y = cb[N_ + n] - m1, z = cb[2 * N_ + n] - m2;
        mx = fmaxf(mx, x * x + y * y + z * z);
    }
    #pragma unroll
    for (int off = 1; off < 64; off <<= 1)
        mx = fmaxf(mx, __shfl_xor(mx, off));
    if ((tid & 63) == 0)
        atomicMax((int*)&bstats[b * 4 + 3], __float_as_int(mx));
}

// ---------------- normalized coords, voxel idx, counts ----------------
__global__ __launch_bounds__(256) void k_point_prep(const float* __restrict__ coords,
                                                    const float* __restrict__ bstats,
                                                    float* __restrict__ nc,
                                                    int* __restrict__ vidx,
                                                    float* __restrict__ cnt) {
    int gid = blockIdx.x * 256 + threadIdx.x;
    int b = gid >> 16;
    int n = gid & (N_ - 1);
    const float invN = 1.0f / (float)N_;
    float m[3] = {bstats[b * 4 + 0] * invN, bstats[b * 4 + 1] * invN, bstats[b * 4 + 2] * invN};
    float den = 2.0f * sqrtf(__int_as_float(((const int*)bstats)[b * 4 + 3]));
    const float* cb = coords + (size_t)b * 3 * N_;
    int vi[3];
    #pragma unroll
    for (int d = 0; d < 3; ++d) {
        float cv = cb[(size_t)d * N_ + n];
        float t = (cv - m[d]) / den + 0.5f;
        t *= 32.0f;
        t = fminf(fmaxf(t, 0.0f), 31.0f);
        nc[((size_t)b * 3 + d) * N_ + n] = t;
        vi[d] = (int)rintf(t);
    }
    int flat = (vi[0] * 32 + vi[1]) * 32 + vi[2];
    vidx[(b << 16) + n] = flat;
    atomicAdd(&cnt[(b << 15) + flat], 1.0f);
}

// ---------------- scatter-add features (channels-last, LDS staged) ----------------
__global__ __launch_bounds__(256) void k_scatter_cl(const float* __restrict__ feats,
                                                    const int* __restrict__ vidx,
                                                    float* __restrict__ gsum) {
    __shared__ float lf[64 * 129];
    __shared__ int sidx[128];
    int tid = threadIdx.x;
    int b = blockIdx.y;
    int n0 = blockIdx.x * 128;
    for (int i = tid; i < 64 * 128; i += 256) {
        int ci = i >> 7, pt = i & 127;
        lf[ci * 129 + pt] = feats[((size_t)(b * 64 + ci)) * N_ + n0 + pt];
    }
    if (tid < 128) sidx[tid] = vidx[(b << 16) + n0 + tid];
    __syncthreads();
    for (int i = tid; i < 64 * 128; i += 256) {
        int ci = i & 63, pt = i >> 6;
        atomicAdd(&gsum[((size_t)(b << 15) + sidx[pt]) * 64 + ci], lf[ci * 129 + pt]);
    }
}

// ---------------- sum -> mean, to padded bf16 channels-last ----------------
__global__ __launch_bounds__(256) void k_gridmean_cl(const float* __restrict__ gsum,
                                                     const float* __restrict__ cnt,
                                                     ushort* __restrict__ gpad) {
    int idx = blockIdx.x * 256 + threadIdx.x;     // 4*32768*16
    int q = idx & 15;
    int vox = (idx >> 4) & 32767;
    int b = idx >> 19;
    float c = cnt[(b << 15) + vox];
    float inv = 1.0f / fmaxf(c, 1.0f);
    float4 v = *(const float4*)(gsum + (((size_t)(b << 15) + vox) << 6) + q * 4);
    int zz = vox >> 10, yy = (vox >> 5) & 31, xx = vox & 31;
    size_t o = ((size_t)b * PADV_ + (size_t)(zz + 1) * PPLANE_ + (yy + 1) * 34 + (xx + 1)) * 64 + q * 4;
    i32x2 pk;
    ushort* u = (ushort*)&pk;
    u[0] = f2bf(v.x * inv); u[1] = f2bf(v.y * inv);
    u[2] = f2bf(v.z * inv); u[3] = f2bf(v.w * inv);
    *(i32x2*)(gpad + o) = pk;
}

// ---------------- weight transform to [chunk][tap][co][32ch] bf16, PLAIN ----------------
template <int CI>
__global__ __launch_bounds__(256) void k_wtrans(const float* __restrict__ w,
                                                ushort* __restrict__ wt) {
    int idx = blockIdx.x * 256 + threadIdx.x;
    if (idx >= 27 * 128 * CI) return;
    int chin = idx & 31;
    int co = (idx >> 5) & 127;
    int t3 = idx >> 12;
    int tap = t3 % 27;
    int chunk = t3 / 27;
    int ci = chunk * 32 + chin;
    wt[idx] = f2bf(w[((size_t)co * CI + ci) * 27 + tap]);
}

// ---------------- 3^3 conv: A-slab once/chunk + 3-page B ring, 1 barrier/tap ----------------
template <int CI, bool PAD_OUT>
__global__ __launch_bounds__(256, 2) void k_conv(const ushort* __restrict__ inp,
                                                 const ushort* __restrict__ wt,
                                                 const float* __restrict__ bias,
                                                 ushort* __restrict__ outp,
                                                 float* __restrict__ gstats,
                                                 int layer) {
    constexpr int NCHUNK = CI / 32;
    __shared__ char lds[65536];            // slab 40960 (incl pad) + 3x8192 ring
    char* ring = lds + 40960;

    const int bid = blockIdx.x;
    const int wid = (bid & 7) * 128 + (bid >> 3);      // 1024 % 8 == 0: bijective
    const int yg = wid & 7;
    const int z0 = (wid >> 3) & 31;
    const int b = wid >> 8;
    const int y0 = yg * 4;
    const int tid = threadIdx.x;
    const int w = tid >> 6, l = tid & 63;
    const int lk = l >> 4, lr = l & 15;
    const int wr = w >> 1, wc = w & 1;

    const char* actb = (const char*)(inp + (size_t)b * PADV_ * CI);
    const char* wtb = (const char*)wt;

    int st_glb[10];
    #pragma unroll
    for (int j = 0; j < 10; ++j) {
        int c = j * 64 + (tid >> 2);
        if (c > 611) c = 611;
        int row = c / 34;
        int x = c - row * 34;
        int dz = row / 6, dy = row - dz * 6;
        int gz = z0 + dz, gy = y0 + dy;
        int lq = (tid & 3) ^ ((x >> 1) & 3);
        st_glb[j] = (gz * PPLANE_ + gy * 34 + x) * CI * 2 + lq * 16;
    }
    int bst[2];
    #pragma unroll
    for (int i = 0; i < 2; ++i) {
        int s = tid + i * 256;
        int q = s & 3, co = s >> 2;
        bst[i] = co * 64 + ((q ^ ((co >> 1) & 3)) << 4);
    }
    int aoff[4][3];
    #pragma unroll
    for (int i = 0; i < 4; ++i) {
        int pos = wr * 64 + i * 16 + lr;
        int ly = pos >> 5, x = pos & 31;
        #pragma unroll
        for (int fx = 0; fx < 3; ++fx) {
            int xc = x + fx;
            aoff[i][fx] = (ly * 34 + xc) * 64 + ((lk ^ ((xc >> 1) & 3)) << 4);
        }
    }
    int boff[4];
    #pragma unroll
    for (int n = 0; n < 4; ++n) {
        int co = wc * 64 + n * 16 + lr;
        boff[n] = co * 64 + ((lk ^ ((co >> 1) & 3)) << 4);
    }

    f32x4 acc[4][4];
    #pragma unroll
    for (int i = 0; i < 4; ++i)
        #pragma unroll
        for (int n = 0; n < 4; ++n)
            acc[i][n] = (f32x4){0.f, 0.f, 0.f, 0.f};

    #pragma unroll 1
    for (int chunk = 0; chunk < NCHUNK; ++chunk) {
        const char* srcb = actb + chunk * 64;
        const char* wch = wtb + (size_t)chunk * 27 * 8192;
        #pragma unroll
        for (int j = 0; j < 10; ++j)
            gl16(srcb + st_glb[j], lds + j * 4096 + w * 1024);
        #pragma unroll
        for (int i = 0; i < 2; ++i)
            gl16(wch + bst[i], ring + i * 4096 + w * 1024);
        #pragma unroll
        for (int i = 0; i < 2; ++i)
            gl16(wch + 8192 + bst[i], ring + 8192 + i * 4096 + w * 1024);

        #pragma unroll
        for (int t = 0; t < 27; ++t) {
            __builtin_amdgcn_sched_barrier(0);
            if (t == 26) {
                asm volatile("s_waitcnt vmcnt(0)" ::: "memory");
            } else {
                asm volatile("s_waitcnt vmcnt(2)" ::: "memory");
            }
            __builtin_amdgcn_sched_barrier(0);
            __builtin_amdgcn_s_barrier();
            __builtin_amdgcn_sched_barrier(0);
            const char* rp = ring + (t % 3) * 8192;
            const int fz = t / 9, r9v = t - fz * 9;
            const int fy = r9v / 3, fx = r9v - fy * 3;
            const int drow = (fz * 6 + fy) * 2176;
            bf16x8 af[4], bfr[4];
            #pragma unroll
            for (int i = 0; i < 4; ++i)
                af[i] = *(const bf16x8*)(lds + drow + aoff[i][fx]);
            #pragma unroll
            for (int n = 0; n < 4; ++n)
                bfr[n] = *(const bf16x8*)(rp + boff[n]);
            __builtin_amdgcn_s_setprio(1);
            #pragma unroll
            for (int i = 0; i < 4; ++i)
                #pragma unroll
                for (int n = 0; n < 4; ++n)
                    acc[i][n] = __builtin_amdgcn_mfma_f32_16x16x32_bf16(af[i], bfr[n], acc[i][n], 0, 0, 0);
            __builtin_amdgcn_s_setprio(0);
            __builtin_amdgcn_sched_barrier(0);
            if (t + 2 < 27) {
                const char* wp = wch + (size_t)(t + 2) * 8192;
                char* rw = ring + ((t + 2) % 3) * 8192;
                #pragma unroll
                for (int i = 0; i < 2; ++i)
                    gl16(wp + bst[i], rw + i * 4096 + w * 1024);
            }
            __builtin_amdgcn_sched_barrier(0);
        }
        __builtin_amdgcn_s_barrier();
        __builtin_amdgcn_sched_barrier(0);
    }

    // ---- epilogue: bias + fused GN stats + bf16 pack via LDS + coalesced dump ----
    ushort* outs = (ushort*)lds;
    float bb[4];
    #pragma unroll
    for (int n = 0; n < 4; ++n) bb[n] = bias[wc * 64 + n * 16 + lr];
    float sg[4] = {0.f, 0.f, 0.f, 0.f}, sq[4] = {0.f, 0.f, 0.f, 0.f};
    #pragma unroll
    for (int i = 0; i < 4; ++i) {
        int posb = wr * 64 + i * 16 + lk * 4;
        #pragma unroll
        for (int n = 0; n < 4; ++n) {
            int co = wc * 64 + n * 16 + lr;
            #pragma unroll
            for (int r = 0; r < 4; ++r) {
                float v = acc[i][n][r] + bb[n];
                sg[n] += v; sq[n] += v * v;
                outs[(posb + r) * 128 + co] = f2bf(v);
            }
        }
    }
    #pragma unroll
    for (int off = 1; off < 64; off <<= 1) {
        #pragma unroll
        for (int n = 0; n < 4; ++n) {
            sg[n] += __shfl_xor(sg[n], off);
            sq[n] += __shfl_xor(sq[n], off);
        }
    }
    if (l == 0) {
        int gbase = layer * 32 + b * 8 + wc * 4;
        #pragma unroll
        for (int n = 0; n < 4; ++n) {
            atomicAdd(&gstats[(gbase + n) * 2 + 0], sg[n]);
            atomicAdd(&gstats[(gbase + n) * 2 + 1], sq[n]);
        }
    }
    __syncthreads();
    for (int idx = tid; idx < 2048; idx += 256) {
        int pos = idx >> 4, c8 = idx & 15;
        int yy = y0 + (pos >> 5), xx = pos & 31;
        size_t g;
        if (PAD_OUT)
            g = ((size_t)b * PADV_ + (size_t)(z0 + 1) * PPLANE_ + (yy + 1) * 34 + (xx + 1)) * 128 + c8 * 8;
        else
            g = ((size_t)b * RRR_ + z0 * 1024 + yy * 32 + xx) * 128 + c8 * 8;
        *(i32x4*)(outp + g) = *((i32x4*)lds + idx);
    }
}

// ---------------- GN + SiLU apply (channels-last bf16, padded) ----------------
template <bool PAD>
__global__ __launch_bounds__(256) void k_gn_apply(ushort* __restrict__ x,
                                                  const float* __restrict__ gstats,
                                                  const float* __restrict__ sc,
                                                  const float* __restrict__ bi,
                                                  int layer, float invc) {
    int idx = blockIdx.x * 256 + threadIdx.x;   // 4*32768*16
    int c8 = idx & 15;
    int vox = (idx >> 4) & 32767;
    int b = idx >> 19;
    size_t base;
    if (PAD) {
        int zz = vox >> 10, yy = (vox >> 5) & 31, xx = vox & 31;
        base = ((size_t)b * PADV_ + (size_t)(zz + 1) * PPLANE_ + (yy + 1) * 34 + (xx + 1)) * 128 + c8 * 8;
    } else {
        base = ((size_t)b * RRR_ + vox) * 128 + c8 * 8;
    }
    int g = c8 >> 1;
    float sum = gstats[(layer * 32 + b * 8 + g) * 2 + 0];
    float ssq = gstats[(layer * 32 + b * 8 + g) * 2 + 1];
    float mean = sum * invc;
    float var = ssq * invc - mean * mean;
    float rstd = rsqrtf(var + 1e-5f);
    i32x4 raw = *(i32x4*)(x + base);
    ushort* u = (ushort*)&raw;
    #pragma unroll
    for (int j = 0; j < 8; ++j) {
        int co = c8 * 8 + j;
        float v = bf2f(u[j]);
        v = (v - mean) * rstd * sc[co] + bi[co];
        v = v / (1.f + __expf(-v));
        u[j] = f2bf(v);
    }
    *(i32x4*)(x + base) = raw;
}

// ---------------- point MLP (1x1 conv) + fused GN stats, bf16 output ----------------
__global__ __launch_bounds__(256) void k_point_mlp(const float* __restrict__ feats,
                                                   const float* __restrict__ w,
                                                   const float* __restrict__ pb,
                                                   ushort* __restrict__ pbf,
                                                   float* __restrict__ gstats) {
    __shared__ float wl[64 * 132];
    __shared__ float sred[4][16];
    int tid = threadIdx.x;
    for (int i = tid; i < 128 * 64; i += 256) {
        int o = i >> 6, c = i & 63;
        wl[c * 132 + o] = w[i];
    }
    __syncthreads();
    int gid = blockIdx.x * 256 + tid;
    int b = gid >> 16, n = gid & (N_ - 1);
    const float* fb = feats + (size_t)b * 64 * N_ + n;
    float acc[128];
    #pragma unroll
    for (int o = 0; o < 128; ++o) acc[o] = 0.f;
    for (int c = 0; c < 64; ++c) {
        float f = fb[(size_t)c * N_];
        const float4* wr4 = (const float4*)&wl[c * 132];
        #pragma unroll
        for (int o4 = 0; o4 < 32; ++o4) {
            float4 wv = wr4[o4];
            acc[4 * o4 + 0] = fmaf(f, wv.x, acc[4 * o4 + 0]);
            acc[4 * o4 + 1] = fmaf(f, wv.y, acc[4 * o4 + 1]);
            acc[4 * o4 + 2] = fmaf(f, wv.z, acc[4 * o4 + 2]);
            acc[4 * o4 + 3] = fmaf(f, wv.w, acc[4 * o4 + 3]);
        }
    }
    ushort* ob = pbf + (size_t)b * 128 * N_ + n;
    float sg[8] = {0.f}, sq[8] = {0.f};
    #pragma unroll
    for (int o = 0; o < 128; ++o) {
        float v = acc[o] + pb[o];
        ob[(size_t)o * N_] = f2bf(v);
        sg[o >> 4] += v;
        sq[o >> 4] += v * v;
    }
    #pragma unroll
    for (int off = 1; off < 64; off <<= 1) {
        #pragma unroll
        for (int g = 0; g < 8; ++g) {
            sg[g] += __shfl_xor(sg[g], off);
            sq[g] += __shfl_xor(sq[g], off);
        }
    }
    int wv = tid >> 6, l = tid & 63;
    if (l == 0) {
        #pragma unroll
        for (int g = 0; g < 8; ++g) { sred[wv][g] = sg[g]; sred[wv][8 + g] = sq[g]; }
    }
    __syncthreads();
    if (tid < 16) {
        float v = sred[0][tid] + sred[1][tid] + sred[2][tid] + sred[3][tid];
        int g = tid & 7, part = tid >> 3;
        atomicAdd(&gstats[(64 + b * 8 + g) * 2 + part], v);
    }
}

// ---------------- devoxelize (fused GN2+SiLU) + point GN/SiLU + add ----------------
__global__ __launch_bounds__(256) void k_devox_final(const float* __restrict__ nc,
                                                     const ushort* __restrict__ ht,
                                                     const ushort* __restrict__ pbf,
                                                     const float* __restrict__ gstats,
                                                     const float* __restrict__ sc2,
                                                     const float* __restrict__ bi2,
                                                     const float* __restrict__ scale,
                                                     const float* __restrict__ bias,
                                                     float* __restrict__ out) {
    __shared__ float vp[64][129];
    __shared__ int sidx[64][8];
    __shared__ float swt[64][8];
    __shared__ float s_sc[128], s_bi[128];
    int tid = threadIdx.x;
    int blk = blockIdx.x;               // 4096; remap: XCD k serves only batch k/2
    int wid = (blk & 7) * 512 + (blk >> 3);   // 4096 % 8 == 0: bijective
    int b = wid >> 10;
    int n0 = (wid & 1023) * 64;
    if (tid < 128) { s_sc[tid] = sc2[tid]; s_bi[tid] = bi2[tid]; }
    if (tid < 64) {
        int n = n0 + tid;
        float f0 = nc[(size_t)b * 3 * N_ + n];
        float f1 = nc[((size_t)b * 3 + 1) * N_ + n];
        float f2 = nc[((size_t)b * 3 + 2) * N_ + n];
        float l0 = floorf(f0), l1 = floorf(f1), l2 = floorf(f2);
        float r0 = f0 - l0, r1 = f1 - l1, r2 = f2 - l2;
        int i0 = (int)l0, i1 = (int)l1, i2 = (int)l2;
        int h0 = min(i0 + 1, 31), h1 = min(i1 + 1, 31), h2 = min(i2 + 1, 31);
        #pragma unroll
        for (int k = 0; k < 8; ++k) {
            int dx = (k >> 2) & 1, dy = (k >> 1) & 1, dz = k & 1;
            int ix = dx ? h0 : i0, iy = dy ? h1 : i1, iz = dz ? h2 : i2;
            float w = (dx ? r0 : 1.f - r0) * (dy ? r1 : 1.f - r1) * (dz ? r2 : 1.f - r2);
            sidx[tid][k] = (ix * 32 + iy) * 32 + iz;
            swt[tid][k] = w;
        }
    }
    __syncthreads();
    const float invcv = 1.0f / (float)(RRR_ * 16);
    const ushort* hb = ht + (size_t)b * RRR_ * 128;
    for (int t = tid; t < 64 * 16; t += 256) {
        int c8 = t & 15, pt = t >> 4;
        // GN2 coefficients for this item's 8 channels (group = c8>>1)
        int g2 = c8 >> 1;
        float sum2 = gstats[(32 + b * 8 + g2) * 2 + 0];
        float ssq2 = gstats[(32 + b * 8 + g2) * 2 + 1];
        float mean2 = sum2 * invcv;
        float var2 = ssq2 * invcv - mean2 * mean2;
        float rstd2 = rsqrtf(var2 + 1e-5f);
        float ca[8], cb2[8];
        #pragma unroll
        for (int j = 0; j < 8; ++j) {
            float s = s_sc[c8 * 8 + j] * rstd2;
            ca[j] = s;
            cb2[j] = s_bi[c8 * 8 + j] - mean2 * s;
        }
        float a[8] = {0.f, 0.f, 0.f, 0.f, 0.f, 0.f, 0.f, 0.f};
        #pragma unroll
        for (int k = 0; k < 8; ++k) {
            i32x4 raw = *(const i32x4*)(hb + (size_t)sidx[pt][k] * 128 + c8 * 8);
            ushort* u = (ushort*)&raw;
            float wk = swt[pt][k];
            #pragma unroll
            for (int j = 0; j < 8; ++j) {
                float v = fmaf(bf2f(u[j]), ca[j], cb2[j]);
                v = v / (1.f + __expf(-v));
                a[j] = fmaf(wk, v, a[j]);
            }
        }
        #pragma unroll
        for (int j = 0; j < 8; ++j)
            vp[pt][c8 * 8 + j] = a[j];
    }
    __syncthreads();
    const float invc = 1.0f / (16.0f * (float)N_);
    for (int t = tid; t < 64 * 128; t += 256) {
        int nl = t & 63;
        int c = t >> 6;
        int g = c >> 4;
        float sum = gstats[(64 + b * 8 + g) * 2 + 0];
        float ssq = gstats[(64 + b * 8 + g) * 2 + 1];
        float mean = sum * invc;
        float var = ssq * invc - mean * mean;
        float rstd = rsqrtf(var + 1e-5f);
        size_t o = ((size_t)(b * 128 + c)) * N_ + n0 + nl;
        float v = (bf2f(pbf[o]) - mean) * rstd * scale[c] + bias[c];
        v = v / (1.f + __expf(-v));
        out[o] = v + vp[nl][c];
    }
}

extern "C" void kernel_launch(void* const* d_in, const int* in_sizes, int n_in,
                              void* d_out, int out_size, void* d_ws, size_t ws_size,
                              hipStream_t stream) {
    const float* coords   = (const float*)d_in[0];
    const float* features = (const float*)d_in[1];
    const float* conv1_w  = (const float*)d_in[2];
    const float* conv1_b  = (const float*)d_in[3];
    const float* gn1_s    = (const float*)d_in[4];
    const float* gn1_b    = (const float*)d_in[5];
    const float* conv2_w  = (const float*)d_in[6];
    const float* conv2_b  = (const float*)d_in[7];
    const float* gn2_s    = (const float*)d_in[8];
    const float* gn2_b    = (const float*)d_in[9];
    const float* point_w  = (const float*)d_in[10];
    const float* point_b  = (const float*)d_in[11];
    const float* pgn_s    = (const float*)d_in[12];
    const float* pgn_b    = (const float*)d_in[13];
    float* out = (float*)d_out;
    float* ws = (float*)d_ws;

    float*  nc     = ws + OFF_NC;
    int*    vidx   = (int*)(ws + OFF_VIDX);
    ushort* wt1    = (ushort*)(ws + OFF_WT1);
    ushort* wt2    = (ushort*)(ws + OFF_WT2);
    ushort* c2out  = (ushort*)(ws + OFF_C2OUT);
    float*  cnt    = ws + OFF_CNT;
    float*  gsum   = ws + OFF_GSUM;
    ushort* gpad   = (ushort*)(ws + OFF_GPAD);
    ushort* act1   = (ushort*)(ws + OFF_ACT1);
    float*  gstats = ws + OFF_GSTATS;
    float*  bstats = ws + OFF_BSTATS;
    ushort* pbf    = (ushort*)(ws + OFF_PBF);   // reuses gsum/gpad/act1 after conv2

    const float invc = 1.0f / (float)(RRR_ * 16);

    // zero only what must be zero: atomic accumulators + stats + buffer halos
    hipMemsetAsync(cnt, 0, MEMSET1_FLOATS * sizeof(float), stream);
    hipMemsetAsync(gstats, 0, (192 + 16) * sizeof(float), stream);
    k_zero_halo<8><<<(B_ * PADV_ * 8 + 255) / 256, 256, 0, stream>>>(gpad);
    k_zero_halo<16><<<(B_ * PADV_ * 16 + 255) / 256, 256, 0, stream>>>(act1);

    k_coord_sum<<<dim3(64, B_), 256, 0, stream>>>(coords, bstats);
    k_coord_max<<<dim3(64, B_), 256, 0, stream>>>(coords, bstats);
    k_point_prep<<<B_ * N_ / 256, 256, 0, stream>>>(coords, bstats, nc, vidx, cnt);
    k_scatter_cl<<<dim3(N_ / 128, B_), 256, 0, stream>>>(features, vidx, gsum);
    k_gridmean_cl<<<B_ * RRR_ * 16 / 256, 256, 0, stream>>>(gsum, cnt, gpad);

    k_wtrans<64><<<(27 * 128 * 64 + 255) / 256, 256, 0, stream>>>(conv1_w, wt1);
    k_wtrans<128><<<(27 * 128 * 128 + 255) / 256, 256, 0, stream>>>(conv2_w, wt2);

    k_conv<64, true><<<1024, 256, 0, stream>>>(gpad, wt1, conv1_b, act1, gstats, 0);
    k_gn_apply<true><<<B_ * RRR_ * 16 / 256, 256, 0, stream>>>(act1, gstats, gn1_s, gn1_b, 0, invc);

    k_conv<128, false><<<1024, 256, 0, stream>>>(act1, wt2, conv2_b, c2out, gstats, 1);
    // GN2+SiLU now fused into k_devox_final's gather (c2out stays raw)

    // point branch AFTER conv2: pbf overlaps gsum/gpad/act1 (dead now)
    k_point_mlp<<<B_ * N_ / 256, 256, 0, stream>>>(features, point_w, point_b, pbf, gstats);
    k_devox_final<<<B_ * N_ / 64, 256, 0, stream>>>(nc, c2out, pbf, gstats,
                                                    gn2_s, gn2_b, pgn_s, pgn_b, out);
}

// Round 20
// 935.166 us; speedup vs baseline: 1.0686x; 1.0686x over previous
//
#include <hip/hip_runtime.h>

typedef __attribute__((ext_vector_type(8))) short bf16x8;
typedef __attribute__((ext_vector_type(4))) float f32x4;
typedef __attribute__((ext_vector_type(4))) int i32x4;
typedef __attribute__((ext_vector_type(2))) int i32x2;

#define B_ 4
#define N_ 65536
#define RRR_ 32768
#define PADV_ 39304   // 34^3
#define PPLANE_ 1156  // 34*34

// ---- workspace layout (float offsets) ----
static const size_t OFF_NC     = 0;         //  [4][3][65536] f32
static const size_t OFF_VIDX   = 786432;    //  [4][65536] int
static const size_t OFF_WT1    = 1048576;   //  [2ch][27][128][32] bf16 PLAIN
static const size_t OFF_WT2    = 1159168;   //  [4ch][27][128][32] bf16 PLAIN
static const size_t OFF_C2OUT  = 1380352;   //  [4][32768][128] bf16
// ---- memset region starts here ----
static const size_t OFF_CNT    = 9768960;   //  [4][32768] f32
static const size_t OFF_GSUM   = 9900032;   //  [4][32768][64] f32
static const size_t OFF_GPAD   = 18288640;  //  [4][39304][64] bf16
static const size_t OFF_ACT1   = 23319552;  //  [4][39304][128] bf16
static const size_t OFF_GSTATS = 33381376;  //  [3][4][8][2] f32 raw sum/ssq
static const size_t OFF_BSTATS = 33381568;  //  [4][4] f32 (sum x3, maxbits)
static const size_t MEMSET_FLOATS = 33381584 - 9768960;
// pbf [4][128][65536] bf16 reuses gsum/gpad/act1 (all dead after conv2)
static const size_t OFF_PBF    = 9900032;

__device__ __forceinline__ ushort f2bf(float x) {
    union { float f; unsigned u; } c; c.f = x;
    unsigned r = c.u + 0x7fffu + ((c.u >> 16) & 1u);
    return (ushort)(r >> 16);
}
__device__ __forceinline__ float bf2f(ushort h) {
    union { unsigned u; float f; } c; c.u = ((unsigned)h) << 16;
    return c.f;
}

__device__ __forceinline__ void gl16(const void* g, void* l) {
    __builtin_amdgcn_global_load_lds(
        (const __attribute__((address_space(1))) unsigned int*)(g),
        (__attribute__((address_space(3))) unsigned int*)(l),
        16, 0, 0);
}

// ---------------- coord partial sums ----------------
__global__ __launch_bounds__(256) void k_coord_sum(const float* __restrict__ coords,
                                                   float* __restrict__ bstats) {
    int b = blockIdx.y;
    int tid = threadIdx.x;
    const float* cb = coords + (size_t)b * 3 * N_;
    float s0 = 0.f, s1 = 0.f, s2 = 0.f;
    for (int n = blockIdx.x * 256 + tid; n < N_; n += 64 * 256) {
        s0 += cb[n]; s1 += cb[N_ + n]; s2 += cb[2 * N_ + n];
    }
    #pragma unroll
    for (int off = 1; off < 64; off <<= 1) {
        s0 += __shfl_xor(s0, off);
        s1 += __shfl_xor(s1, off);
        s2 += __shfl_xor(s2, off);
    }
    if ((tid & 63) == 0) {
        atomicAdd(&bstats[b * 4 + 0], s0);
        atomicAdd(&bstats[b * 4 + 1], s1);
        atomicAdd(&bstats[b * 4 + 2], s2);
    }
}

// ---------------- coord max-norm (after sums) ----------------
__global__ __launch_bounds__(256) void k_coord_max(const float* __restrict__ coords,
                                                   float* __restrict__ bstats) {
    int b = blockIdx.y;
    int tid = threadIdx.x;
    const float invN = 1.0f / (float)N_;
    float m0 = bstats[b * 4 + 0] * invN;
    float m1 = bstats[b * 4 + 1] * invN;
    float m2 = bstats[b * 4 + 2] * invN;
    const float* cb = coords + (size_t)b * 3 * N_;
    float mx = 0.f;
    for (int n = blockIdx.x * 256 + tid; n < N_; n += 64 * 256) {
        float x = cb[n] - m0, y = cb[N_ + n] - m1, z = cb[2 * N_ + n] - m2;
        mx = fmaxf(mx, x * x + y * y + z * z);
    }
    #pragma unroll
    for (int off = 1; off < 64; off <<= 1)
        mx = fmaxf(mx, __shfl_xor(mx, off));
    if ((tid & 63) == 0)
        atomicMax((int*)&bstats[b * 4 + 3], __float_as_int(mx));
}

// ---------------- normalized coords, voxel idx, counts ----------------
__global__ __launch_bounds__(256) void k_point_prep(const float* __restrict__ coords,
                                                    const float* __restrict__ bstats,
                                                    float* __restrict__ nc,
                                                    int* __restrict__ vidx,
                                                    float* __restrict__ cnt) {
    int gid = blockIdx.x * 256 + threadIdx.x;
    int b = gid >> 16;
    int n = gid & (N_ - 1);
    const float invN = 1.0f / (float)N_;
    float m[3] = {bstats[b * 4 + 0] * invN, bstats[b * 4 + 1] * invN, bstats[b * 4 + 2] * invN};
    float den = 2.0f * sqrtf(__int_as_float(((const int*)bstats)[b * 4 + 3]));
    const float* cb = coords + (size_t)b * 3 * N_;
    int vi[3];
    #pragma unroll
    for (int d = 0; d < 3; ++d) {
        float cv = cb[(size_t)d * N_ + n];
        float t = (cv - m[d]) / den + 0.5f;
        t *= 32.0f;
        t = fminf(fmaxf(t, 0.0f), 31.0f);
        nc[((size_t)b * 3 + d) * N_ + n] = t;
        vi[d] = (int)rintf(t);
    }
    int flat = (vi[0] * 32 + vi[1]) * 32 + vi[2];
    vidx[(b << 16) + n] = flat;
    atomicAdd(&cnt[(b << 15) + flat], 1.0f);
}

// ---------------- scatter-add features (channels-last, LDS staged) ----------------
__global__ __launch_bounds__(256) void k_scatter_cl(const float* __restrict__ feats,
                                                    const int* __restrict__ vidx,
                                                    float* __restrict__ gsum) {
    __shared__ float lf[64 * 129];
    __shared__ int sidx[128];
    int tid = threadIdx.x;
    int b = blockIdx.y;
    int n0 = blockIdx.x * 128;
    for (int i = tid; i < 64 * 128; i += 256) {
        int ci = i >> 7, pt = i & 127;
        lf[ci * 129 + pt] = feats[((size_t)(b * 64 + ci)) * N_ + n0 + pt];
    }
    if (tid < 128) sidx[tid] = vidx[(b << 16) + n0 + tid];
    __syncthreads();
    for (int i = tid; i < 64 * 128; i += 256) {
        int ci = i & 63, pt = i >> 6;
        atomicAdd(&gsum[((size_t)(b << 15) + sidx[pt]) * 64 + ci], lf[ci * 129 + pt]);
    }
}

// ---------------- sum -> mean, to padded bf16 channels-last ----------------
__global__ __launch_bounds__(256) void k_gridmean_cl(const float* __restrict__ gsum,
                                                     const float* __restrict__ cnt,
                                                     ushort* __restrict__ gpad) {
    int idx = blockIdx.x * 256 + threadIdx.x;     // 4*32768*16
    int q = idx & 15;
    int vox = (idx >> 4) & 32767;
    int b = idx >> 19;
    float c = cnt[(b << 15) + vox];
    float inv = 1.0f / fmaxf(c, 1.0f);
    float4 v = *(const float4*)(gsum + (((size_t)(b << 15) + vox) << 6) + q * 4);
    int zz = vox >> 10, yy = (vox >> 5) & 31, xx = vox & 31;
    size_t o = ((size_t)b * PADV_ + (size_t)(zz + 1) * PPLANE_ + (yy + 1) * 34 + (xx + 1)) * 64 + q * 4;
    i32x2 pk;
    ushort* u = (ushort*)&pk;
    u[0] = f2bf(v.x * inv); u[1] = f2bf(v.y * inv);
    u[2] = f2bf(v.z * inv); u[3] = f2bf(v.w * inv);
    *(i32x2*)(gpad + o) = pk;
}

// ---------------- weight transform to [chunk][tap][co][32ch] bf16, PLAIN ----------------
template <int CI>
__global__ __launch_bounds__(256) void k_wtrans(const float* __restrict__ w,
                                                ushort* __restrict__ wt) {
    int idx = blockIdx.x * 256 + threadIdx.x;
    if (idx >= 27 * 128 * CI) return;
    int chin = idx & 31;
    int co = (idx >> 5) & 127;
    int t3 = idx >> 12;
    int tap = t3 % 27;
    int chunk = t3 / 27;
    int ci = chunk * 32 + chin;
    wt[idx] = f2bf(w[((size_t)co * CI + ci) * 27 + tap]);
}

// ---------------- 3^3 conv: A-slab once/chunk + 3-page B ring, 1 barrier/tap ----------------
// block: 128 pos x 128 co, 256 thr / 4 waves, 2 blocks/CU (LDS = 64KB exactly).
// Per tap: vmcnt(2) [B(t) landed] -> s_barrier -> 16 MFMA (setprio) -> issue B(t+2)
// into page (t+2)%3. B swizzle (co>>1)&3 on BOTH stage & read: conflict-free.
template <int CI, bool PAD_OUT>
__global__ __launch_bounds__(256, 2) void k_conv(const ushort* __restrict__ inp,
                                                 const ushort* __restrict__ wt,
                                                 const float* __restrict__ bias,
                                                 ushort* __restrict__ outp,
                                                 float* __restrict__ gstats,
                                                 int layer) {
    constexpr int NCHUNK = CI / 32;
    __shared__ char lds[65536];            // slab 40960 (incl pad) + 3x8192 ring
    char* ring = lds + 40960;

    const int bid = blockIdx.x;
    const int wid = (bid & 7) * 128 + (bid >> 3);      // 1024 % 8 == 0: bijective
    const int yg = wid & 7;
    const int z0 = (wid >> 3) & 31;
    const int b = wid >> 8;
    const int y0 = yg * 4;
    const int tid = threadIdx.x;
    const int w = tid >> 6, l = tid & 63;
    const int lk = l >> 4, lr = l & 15;
    const int wr = w >> 1, wc = w & 1;

    const char* actb = (const char*)(inp + (size_t)b * PADV_ * CI);
    const char* wtb = (const char*)wt;

    int st_glb[10];
    #pragma unroll
    for (int j = 0; j < 10; ++j) {
        int c = j * 64 + (tid >> 2);
        if (c > 611) c = 611;
        int row = c / 34;
        int x = c - row * 34;
        int dz = row / 6, dy = row - dz * 6;
        int gz = z0 + dz, gy = y0 + dy;
        int lq = (tid & 3) ^ ((x >> 1) & 3);
        st_glb[j] = (gz * PPLANE_ + gy * 34 + x) * CI * 2 + lq * 16;
    }
    int bst[2];
    #pragma unroll
    for (int i = 0; i < 2; ++i) {
        int s = tid + i * 256;
        int q = s & 3, co = s >> 2;
        bst[i] = co * 64 + ((q ^ ((co >> 1) & 3)) << 4);
    }
    int aoff[4][3];
    #pragma unroll
    for (int i = 0; i < 4; ++i) {
        int pos = wr * 64 + i * 16 + lr;
        int ly = pos >> 5, x = pos & 31;
        #pragma unroll
        for (int fx = 0; fx < 3; ++fx) {
            int xc = x + fx;
            aoff[i][fx] = (ly * 34 + xc) * 64 + ((lk ^ ((xc >> 1) & 3)) << 4);
        }
    }
    int boff[4];
    #pragma unroll
    for (int n = 0; n < 4; ++n) {
        int co = wc * 64 + n * 16 + lr;
        boff[n] = co * 64 + ((lk ^ ((co >> 1) & 3)) << 4);
    }

    f32x4 acc[4][4];
    #pragma unroll
    for (int i = 0; i < 4; ++i)
        #pragma unroll
        for (int n = 0; n < 4; ++n)
            acc[i][n] = (f32x4){0.f, 0.f, 0.f, 0.f};

    #pragma unroll 1
    for (int chunk = 0; chunk < NCHUNK; ++chunk) {
        const char* srcb = actb + chunk * 64;
        const char* wch = wtb + (size_t)chunk * 27 * 8192;
        #pragma unroll
        for (int j = 0; j < 10; ++j)
            gl16(srcb + st_glb[j], lds + j * 4096 + w * 1024);
        #pragma unroll
        for (int i = 0; i < 2; ++i)
            gl16(wch + bst[i], ring + i * 4096 + w * 1024);
        #pragma unroll
        for (int i = 0; i < 2; ++i)
            gl16(wch + 8192 + bst[i], ring + 8192 + i * 4096 + w * 1024);

        #pragma unroll
        for (int t = 0; t < 27; ++t) {
            __builtin_amdgcn_sched_barrier(0);
            if (t == 26) {
                asm volatile("s_waitcnt vmcnt(0)" ::: "memory");
            } else {
                asm volatile("s_waitcnt vmcnt(2)" ::: "memory");
            }
            __builtin_amdgcn_sched_barrier(0);
            __builtin_amdgcn_s_barrier();
            __builtin_amdgcn_sched_barrier(0);
            const char* rp = ring + (t % 3) * 8192;
            const int fz = t / 9, r9v = t - fz * 9;
            const int fy = r9v / 3, fx = r9v - fy * 3;
            const int drow = (fz * 6 + fy) * 2176;
            bf16x8 af[4], bfr[4];
            #pragma unroll
            for (int i = 0; i < 4; ++i)
                af[i] = *(const bf16x8*)(lds + drow + aoff[i][fx]);
            #pragma unroll
            for (int n = 0; n < 4; ++n)
                bfr[n] = *(const bf16x8*)(rp + boff[n]);
            __builtin_amdgcn_s_setprio(1);
            #pragma unroll
            for (int i = 0; i < 4; ++i)
                #pragma unroll
                for (int n = 0; n < 4; ++n)
                    acc[i][n] = __builtin_amdgcn_mfma_f32_16x16x32_bf16(af[i], bfr[n], acc[i][n], 0, 0, 0);
            __builtin_amdgcn_s_setprio(0);
            __builtin_amdgcn_sched_barrier(0);
            if (t + 2 < 27) {
                const char* wp = wch + (size_t)(t + 2) * 8192;
                char* rw = ring + ((t + 2) % 3) * 8192;
                #pragma unroll
                for (int i = 0; i < 2; ++i)
                    gl16(wp + bst[i], rw + i * 4096 + w * 1024);
            }
            __builtin_amdgcn_sched_barrier(0);
        }
        __builtin_amdgcn_s_barrier();
        __builtin_amdgcn_sched_barrier(0);
    }

    // ---- epilogue: bias + fused GN stats + bf16 pack via LDS + coalesced dump ----
    ushort* outs = (ushort*)lds;
    float bb[4];
    #pragma unroll
    for (int n = 0; n < 4; ++n) bb[n] = bias[wc * 64 + n * 16 + lr];
    float sg[4] = {0.f, 0.f, 0.f, 0.f}, sq[4] = {0.f, 0.f, 0.f, 0.f};
    #pragma unroll
    for (int i = 0; i < 4; ++i) {
        int posb = wr * 64 + i * 16 + lk * 4;
        #pragma unroll
        for (int n = 0; n < 4; ++n) {
            int co = wc * 64 + n * 16 + lr;
            #pragma unroll
            for (int r = 0; r < 4; ++r) {
                float v = acc[i][n][r] + bb[n];
                sg[n] += v; sq[n] += v * v;
                outs[(posb + r) * 128 + co] = f2bf(v);
            }
        }
    }
    #pragma unroll
    for (int off = 1; off < 64; off <<= 1) {
        #pragma unroll
        for (int n = 0; n < 4; ++n) {
            sg[n] += __shfl_xor(sg[n], off);
            sq[n] += __shfl_xor(sq[n], off);
        }
    }
    if (l == 0) {
        int gbase = layer * 32 + b * 8 + wc * 4;
        #pragma unroll
        for (int n = 0; n < 4; ++n) {
            atomicAdd(&gstats[(gbase + n) * 2 + 0], sg[n]);
            atomicAdd(&gstats[(gbase + n) * 2 + 1], sq[n]);
        }
    }
    __syncthreads();
    for (int idx = tid; idx < 2048; idx += 256) {
        int pos = idx >> 4, c8 = idx & 15;
        int yy = y0 + (pos >> 5), xx = pos & 31;
        size_t g;
        if (PAD_OUT)
            g = ((size_t)b * PADV_ + (size_t)(z0 + 1) * PPLANE_ + (yy + 1) * 34 + (xx + 1)) * 128 + c8 * 8;
        else
            g = ((size_t)b * RRR_ + z0 * 1024 + yy * 32 + xx) * 128 + c8 * 8;
        *(i32x4*)(outp + g) = *((i32x4*)lds + idx);
    }
}

// ---------------- GN + SiLU apply (channels-last bf16, padded or flat) ----------------
template <bool PAD>
__global__ __launch_bounds__(256) void k_gn_apply(ushort* __restrict__ x,
                                                  const float* __restrict__ gstats,
                                                  const float* __restrict__ sc,
                                                  const float* __restrict__ bi,
                                                  int layer, float invc) {
    int idx = blockIdx.x * 256 + threadIdx.x;   // 4*32768*16
    int c8 = idx & 15;
    int vox = (idx >> 4) & 32767;
    int b = idx >> 19;
    size_t base;
    if (PAD) {
        int zz = vox >> 10, yy = (vox >> 5) & 31, xx = vox & 31;
        base = ((size_t)b * PADV_ + (size_t)(zz + 1) * PPLANE_ + (yy + 1) * 34 + (xx + 1)) * 128 + c8 * 8;
    } else {
        base = ((size_t)b * RRR_ + vox) * 128 + c8 * 8;
    }
    int g = c8 >> 1;
    float sum = gstats[(layer * 32 + b * 8 + g) * 2 + 0];
    float ssq = gstats[(layer * 32 + b * 8 + g) * 2 + 1];
    float mean = sum * invc;
    float var = ssq * invc - mean * mean;
    float rstd = rsqrtf(var + 1e-5f);
    i32x4 raw = *(i32x4*)(x + base);
    ushort* u = (ushort*)&raw;
    #pragma unroll
    for (int j = 0; j < 8; ++j) {
        int co = c8 * 8 + j;
        float v = bf2f(u[j]);
        v = (v - mean) * rstd * sc[co] + bi[co];
        v = v / (1.f + __expf(-v));
        u[j] = f2bf(v);
    }
    *(i32x4*)(x + base) = raw;
}

// ---------------- point MLP (1x1 conv) + fused GN stats, bf16 output ----------------
__global__ __launch_bounds__(256) void k_point_mlp(const float* __restrict__ feats,
                                                   const float* __restrict__ w,
                                                   const float* __restrict__ pb,
                                                   ushort* __restrict__ pbf,
                                                   float* __restrict__ gstats) {
    __shared__ float wl[64 * 132];
    __shared__ float sred[4][16];
    int tid = threadIdx.x;
    for (int i = tid; i < 128 * 64; i += 256) {
        int o = i >> 6, c = i & 63;
        wl[c * 132 + o] = w[i];
    }
    __syncthreads();
    int gid = blockIdx.x * 256 + tid;
    int b = gid >> 16, n = gid & (N_ - 1);
    const float* fb = feats + (size_t)b * 64 * N_ + n;
    float acc[128];
    #pragma unroll
    for (int o = 0; o < 128; ++o) acc[o] = 0.f;
    for (int c = 0; c < 64; ++c) {
        float f = fb[(size_t)c * N_];
        const float4* wr4 = (const float4*)&wl[c * 132];
        #pragma unroll
        for (int o4 = 0; o4 < 32; ++o4) {
            float4 wv = wr4[o4];
            acc[4 * o4 + 0] = fmaf(f, wv.x, acc[4 * o4 + 0]);
            acc[4 * o4 + 1] = fmaf(f, wv.y, acc[4 * o4 + 1]);
            acc[4 * o4 + 2] = fmaf(f, wv.z, acc[4 * o4 + 2]);
            acc[4 * o4 + 3] = fmaf(f, wv.w, acc[4 * o4 + 3]);
        }
    }
    ushort* ob = pbf + (size_t)b * 128 * N_ + n;
    float sg[8] = {0.f}, sq[8] = {0.f};
    #pragma unroll
    for (int o = 0; o < 128; ++o) {
        float v = acc[o] + pb[o];
        ob[(size_t)o * N_] = f2bf(v);
        sg[o >> 4] += v;
        sq[o >> 4] += v * v;
    }
    #pragma unroll
    for (int off = 1; off < 64; off <<= 1) {
        #pragma unroll
        for (int g = 0; g < 8; ++g) {
            sg[g] += __shfl_xor(sg[g], off);
            sq[g] += __shfl_xor(sq[g], off);
        }
    }
    int wv = tid >> 6, l = tid & 63;
    if (l == 0) {
        #pragma unroll
        for (int g = 0; g < 8; ++g) { sred[wv][g] = sg[g]; sred[wv][8 + g] = sq[g]; }
    }
    __syncthreads();
    if (tid < 16) {
        float v = sred[0][tid] + sred[1][tid] + sred[2][tid] + sred[3][tid];
        int g = tid & 7, part = tid >> 3;
        atomicAdd(&gstats[(64 + b * 8 + g) * 2 + part], v);
    }
}

// ---------------- devoxelize + point GN/SiLU + add; XCD-batch affinity ----------------
__global__ __launch_bounds__(256) void k_devox_final(const float* __restrict__ nc,
                                                     const ushort* __restrict__ ht,
                                                     const ushort* __restrict__ pbf,
                                                     const float* __restrict__ gstats,
                                                     const float* __restrict__ scale,
                                                     const float* __restrict__ bias,
                                                     float* __restrict__ out) {
    __shared__ float vp[64][129];
    __shared__ int sidx[64][8];
    __shared__ float swt[64][8];
    int tid = threadIdx.x;
    int blk = blockIdx.x;               // 4096; remap: XCD k serves only batch k/2
    int wid = (blk & 7) * 512 + (blk >> 3);   // 4096 % 8 == 0: bijective
    int b = wid >> 10;
    int n0 = (wid & 1023) * 64;
    if (tid < 64) {
        int n = n0 + tid;
        float f0 = nc[(size_t)b * 3 * N_ + n];
        float f1 = nc[((size_t)b * 3 + 1) * N_ + n];
        float f2 = nc[((size_t)b * 3 + 2) * N_ + n];
        float l0 = floorf(f0), l1 = floorf(f1), l2 = floorf(f2);
        float r0 = f0 - l0, r1 = f1 - l1, r2 = f2 - l2;
        int i0 = (int)l0, i1 = (int)l1, i2 = (int)l2;
        int h0 = min(i0 + 1, 31), h1 = min(i1 + 1, 31), h2 = min(i2 + 1, 31);
        #pragma unroll
        for (int k = 0; k < 8; ++k) {
            int dx = (k >> 2) & 1, dy = (k >> 1) & 1, dz = k & 1;
            int ix = dx ? h0 : i0, iy = dy ? h1 : i1, iz = dz ? h2 : i2;
            float w = (dx ? r0 : 1.f - r0) * (dy ? r1 : 1.f - r1) * (dz ? r2 : 1.f - r2);
            sidx[tid][k] = (ix * 32 + iy) * 32 + iz;
            swt[tid][k] = w;
        }
    }
    __syncthreads();
    const ushort* hb = ht + (size_t)b * RRR_ * 128;
    for (int t = tid; t < 64 * 16; t += 256) {
        int c8 = t & 15, pt = t >> 4;
        float a[8] = {0.f, 0.f, 0.f, 0.f, 0.f, 0.f, 0.f, 0.f};
        #pragma unroll
        for (int k = 0; k < 8; ++k) {
            i32x4 raw = *(const i32x4*)(hb + (size_t)sidx[pt][k] * 128 + c8 * 8);
            ushort* u = (ushort*)&raw;
            float wk = swt[pt][k];
            #pragma unroll
            for (int j = 0; j < 8; ++j)
                a[j] = fmaf(wk, bf2f(u[j]), a[j]);
        }
        #pragma unroll
        for (int j = 0; j < 8; ++j)
            vp[pt][c8 * 8 + j] = a[j];
    }
    __syncthreads();
    const float invc = 1.0f / (16.0f * (float)N_);
    for (int t = tid; t < 64 * 128; t += 256) {
        int nl = t & 63;
        int c = t >> 6;
        int g = c >> 4;
        float sum = gstats[(64 + b * 8 + g) * 2 + 0];
        float ssq = gstats[(64 + b * 8 + g) * 2 + 1];
        float mean = sum * invc;
        float var = ssq * invc - mean * mean;
        float rstd = rsqrtf(var + 1e-5f);
        size_t o = ((size_t)(b * 128 + c)) * N_ + n0 + nl;
        float v = (bf2f(pbf[o]) - mean) * rstd * scale[c] + bias[c];
        v = v / (1.f + __expf(-v));
        out[o] = v + vp[nl][c];
    }
}

extern "C" void kernel_launch(void* const* d_in, const int* in_sizes, int n_in,
                              void* d_out, int out_size, void* d_ws, size_t ws_size,
                              hipStream_t stream) {
    const float* coords   = (const float*)d_in[0];
    const float* features = (const float*)d_in[1];
    const float* conv1_w  = (const float*)d_in[2];
    const float* conv1_b  = (const float*)d_in[3];
    const float* gn1_s    = (const float*)d_in[4];
    const float* gn1_b    = (const float*)d_in[5];
    const float* conv2_w  = (const float*)d_in[6];
    const float* conv2_b  = (const float*)d_in[7];
    const float* gn2_s    = (const float*)d_in[8];
    const float* gn2_b    = (const float*)d_in[9];
    const float* point_w  = (const float*)d_in[10];
    const float* point_b  = (const float*)d_in[11];
    const float* pgn_s    = (const float*)d_in[12];
    const float* pgn_b    = (const float*)d_in[13];
    float* out = (float*)d_out;
    float* ws = (float*)d_ws;

    float*  nc     = ws + OFF_NC;
    int*    vidx   = (int*)(ws + OFF_VIDX);
    ushort* wt1    = (ushort*)(ws + OFF_WT1);
    ushort* wt2    = (ushort*)(ws + OFF_WT2);
    ushort* c2out  = (ushort*)(ws + OFF_C2OUT);
    float*  cnt    = ws + OFF_CNT;
    float*  gsum   = ws + OFF_GSUM;
    ushort* gpad   = (ushort*)(ws + OFF_GPAD);
    ushort* act1   = (ushort*)(ws + OFF_ACT1);
    float*  gstats = ws + OFF_GSTATS;
    float*  bstats = ws + OFF_BSTATS;
    ushort* pbf    = (ushort*)(ws + OFF_PBF);   // reuses gsum/gpad/act1 after conv2

    const float invc = 1.0f / (float)(RRR_ * 16);

    hipMemsetAsync(cnt, 0, MEMSET_FLOATS * sizeof(float), stream);

    k_coord_sum<<<dim3(64, B_), 256, 0, stream>>>(coords, bstats);
    k_coord_max<<<dim3(64, B_), 256, 0, stream>>>(coords, bstats);
    k_point_prep<<<B_ * N_ / 256, 256, 0, stream>>>(coords, bstats, nc, vidx, cnt);
    k_scatter_cl<<<dim3(N_ / 128, B_), 256, 0, stream>>>(features, vidx, gsum);
    k_gridmean_cl<<<B_ * RRR_ * 16 / 256, 256, 0, stream>>>(gsum, cnt, gpad);

    k_wtrans<64><<<(27 * 128 * 64 + 255) / 256, 256, 0, stream>>>(conv1_w, wt1);
    k_wtrans<128><<<(27 * 128 * 128 + 255) / 256, 256, 0, stream>>>(conv2_w, wt2);

    k_conv<64, true><<<1024, 256, 0, stream>>>(gpad, wt1, conv1_b, act1, gstats, 0);
    k_gn_apply<true><<<B_ * RRR_ * 16 / 256, 256, 0, stream>>>(act1, gstats, gn1_s, gn1_b, 0, invc);

    k_conv<128, false><<<1024, 256, 0, stream>>>(act1, wt2, conv2_b, c2out, gstats, 1);
    k_gn_apply<false><<<B_ * RRR_ * 16 / 256, 256, 0, stream>>>(c2out, gstats, gn2_s, gn2_b, 1, invc);

    // point branch AFTER conv2: pbf overlaps gsum/gpad/act1 (dead now)
    k_point_mlp<<<B_ * N_ / 256, 256, 0, stream>>>(features, point_w, point_b, pbf, gstats);
    k_devox_final<<<B_ * N_ / 64, 256, 0, stream>>>(nc, c2out, pbf, gstats, pgn_s, pgn_b, out);
}

// Round 21
// 934.112 us; speedup vs baseline: 1.0698x; 1.0011x over previous
//
#include <hip/hip_runtime.h>

typedef __attribute__((ext_vector_type(8))) short bf16x8;
typedef __attribute__((ext_vector_type(4))) float f32x4;
typedef __attribute__((ext_vector_type(4))) int i32x4;
typedef __attribute__((ext_vector_type(2))) int i32x2;

#define B_ 4
#define N_ 65536
#define RRR_ 32768
#define PADV_ 39304   // 34^3
#define PPLANE_ 1156  // 34*34

// ---- workspace layout (float offsets) ----
static const size_t OFF_NC     = 0;         //  [4][3][65536] f32
static const size_t OFF_VIDX   = 786432;    //  [4][65536] int
static const size_t OFF_WT1    = 1048576;   //  [2ch][27][128][32] bf16 PLAIN
static const size_t OFF_WT2    = 1159168;   //  [4ch][27][128][32] bf16 PLAIN
static const size_t OFF_C2OUT  = 1380352;   //  [4][32768][128] bf16
static const size_t OFF_CNT    = 9768960;   //  [4][32768] f32        (memset)
static const size_t OFF_GSUM   = 9900032;   //  [4][32768][64] f32    (memset)
static const size_t OFF_GPAD   = 18288640;  //  [4][39304][64] bf16   (halo-zeroed)
static const size_t OFF_ACT1   = 23319552;  //  [4][39304][128] bf16  (halo-zeroed)
static const size_t OFF_GSTATS = 33381376;  //  [3][4][8][2] f32 raw sum/ssq (memset)
static const size_t OFF_BSTATS = 33381568;  //  [4][4] f32 (sum x3, maxbits) (memset)
static const size_t MEMSET1_FLOATS = 131072 + 8388608;   // cnt + gsum
// pbf [4][128][65536] bf16 reuses gsum/gpad/act1 (all dead after conv2)
static const size_t OFF_PBF    = 9900032;

__device__ __forceinline__ ushort f2bf(float x) {
    union { float f; unsigned u; } c; c.f = x;
    unsigned r = c.u + 0x7fffu + ((c.u >> 16) & 1u);
    return (ushort)(r >> 16);
}
__device__ __forceinline__ float bf2f(ushort h) {
    union { unsigned u; float f; } c; c.u = ((unsigned)h) << 16;
    return c.f;
}

__device__ __forceinline__ void gl16(const void* g, void* l) {
    __builtin_amdgcn_global_load_lds(
        (const __attribute__((address_space(1))) unsigned int*)(g),
        (__attribute__((address_space(3))) unsigned int*)(l),
        16, 0, 0);
}

// ---------------- zero only the halo cells of a padded channels-last buffer ----------------
template <int CH8>
__global__ __launch_bounds__(256) void k_zero_halo(ushort* __restrict__ buf) {
    int idx = blockIdx.x * 256 + threadIdx.x;       // B * PADV * CH8
    if (idx >= B_ * PADV_ * CH8) return;
    int c8 = idx % CH8;
    int t = idx / CH8;
    int vox = t % PADV_;
    int b = t / PADV_;
    int z = vox / PPLANE_;
    int rem = vox - z * PPLANE_;
    int y = rem / 34;
    int x = rem - y * 34;
    if (z == 0 || z == 33 || y == 0 || y == 33 || x == 0 || x == 33) {
        i32x4 zero = (i32x4){0, 0, 0, 0};
        *(i32x4*)(buf + ((size_t)b * PADV_ + vox) * (CH8 * 8) + c8 * 8) = zero;
    }
}

// ---------------- coord partial sums ----------------
__global__ __launch_bounds__(256) void k_coord_sum(const float* __restrict__ coords,
                                                   float* __restrict__ bstats) {
    int b = blockIdx.y;
    int tid = threadIdx.x;
    const float* cb = coords + (size_t)b * 3 * N_;
    float s0 = 0.f, s1 = 0.f, s2 = 0.f;
    for (int n = blockIdx.x * 256 + tid; n < N_; n += 64 * 256) {
        s0 += cb[n]; s1 += cb[N_ + n]; s2 += cb[2 * N_ + n];
    }
    #pragma unroll
    for (int off = 1; off < 64; off <<= 1) {
        s0 += __shfl_xor(s0, off);
        s1 += __shfl_xor(s1, off);
        s2 += __shfl_xor(s2, off);
    }
    if ((tid & 63) == 0) {
        atomicAdd(&bstats[b * 4 + 0], s0);
        atomicAdd(&bstats[b * 4 + 1], s1);
        atomicAdd(&bstats[b * 4 + 2], s2);
    }
}

// ---------------- coord max-norm (after sums) ----------------
__global__ __launch_bounds__(256) void k_coord_max(const float* __restrict__ coords,
                                                   float* __restrict__ bstats) {
    int b = blockIdx.y;
    int tid = threadIdx.x;
    const float invN = 1.0f / (float)N_;
    float m0 = bstats[b * 4 + 0] * invN;
    float m1 = bstats[b * 4 + 1] * invN;
    float m2 = bstats[b * 4 + 2] * invN;
    const float* cb = coords + (size_t)b * 3 * N_;
    float mx = 0.f;
    for (int n = blockIdx.x * 256 + tid; n < N_; n += 64 * 256) {
        float x = cb[n] - m0, y = cb[N_ + n] - m1, z = cb[2 * N_ + n] - m2;
        mx = fmaxf(mx, x * x + y * y + z * z);
    }
    #pragma unroll
    for (int off = 1; off < 64; off <<= 1)
        mx = fmaxf(mx, __shfl_xor(mx, off));
    if ((tid & 63) == 0)
        atomicMax((int*)&bstats[b * 4 + 3], __float_as_int(mx));
}

// ---------------- normalized coords, voxel idx, counts ----------------
__global__ __launch_bounds__(256) void k_point_prep(const float* __restrict__ coords,
                                                    const float* __restrict__ bstats,
                                                    float* __restrict__ nc,
                                                    int* __restrict__ vidx,
                                                    float* __restrict__ cnt) {
    int gid = blockIdx.x * 256 + threadIdx.x;
    int b = gid >> 16;
    int n = gid & (N_ - 1);
    const float invN = 1.0f / (float)N_;
    float m[3] = {bstats[b * 4 + 0] * invN, bstats[b * 4 + 1] * invN, bstats[b * 4 + 2] * invN};
    float den = 2.0f * sqrtf(__int_as_float(((const int*)bstats)[b * 4 + 3]));
    const float* cb = coords + (size_t)b * 3 * N_;
    int vi[3];
    #pragma unroll
    for (int d = 0; d < 3; ++d) {
        float cv = cb[(size_t)d * N_ + n];
        float t = (cv - m[d]) / den + 0.5f;
        t *= 32.0f;
        t = fminf(fmaxf(t, 0.0f), 31.0f);
        nc[((size_t)b * 3 + d) * N_ + n] = t;
        vi[d] = (int)rintf(t);
    }
    int flat = (vi[0] * 32 + vi[1]) * 32 + vi[2];
    vidx[(b << 16) + n] = flat;
    atomicAdd(&cnt[(b << 15) + flat], 1.0f);
}

// ---------------- scatter-add features (channels-last, LDS staged) ----------------
__global__ __launch_bounds__(256) void k_scatter_cl(const float* __restrict__ feats,
                                                    const int* __restrict__ vidx,
                                                    float* __restrict__ gsum) {
    __shared__ float lf[64 * 129];
    __shared__ int sidx[128];
    int tid = threadIdx.x;
    int b = blockIdx.y;
    int n0 = blockIdx.x * 128;
    for (int i = tid; i < 64 * 128; i += 256) {
        int ci = i >> 7, pt = i & 127;
        lf[ci * 129 + pt] = feats[((size_t)(b * 64 + ci)) * N_ + n0 + pt];
    }
    if (tid < 128) sidx[tid] = vidx[(b << 16) + n0 + tid];
    __syncthreads();
    for (int i = tid; i < 64 * 128; i += 256) {
        int ci = i & 63, pt = i >> 6;
        atomicAdd(&gsum[((size_t)(b << 15) + sidx[pt]) * 64 + ci], lf[ci * 129 + pt]);
    }
}

// ---------------- sum -> mean, to padded bf16 channels-last ----------------
__global__ __launch_bounds__(256) void k_gridmean_cl(const float* __restrict__ gsum,
                                                     const float* __restrict__ cnt,
                                                     ushort* __restrict__ gpad) {
    int idx = blockIdx.x * 256 + threadIdx.x;     // 4*32768*16
    int q = idx & 15;
    int vox = (idx >> 4) & 32767;
    int b = idx >> 19;
    float c = cnt[(b << 15) + vox];
    float inv = 1.0f / fmaxf(c, 1.0f);
    float4 v = *(const float4*)(gsum + (((size_t)(b << 15) + vox) << 6) + q * 4);
    int zz = vox >> 10, yy = (vox >> 5) & 31, xx = vox & 31;
    size_t o = ((size_t)b * PADV_ + (size_t)(zz + 1) * PPLANE_ + (yy + 1) * 34 + (xx + 1)) * 64 + q * 4;
    i32x2 pk;
    ushort* u = (ushort*)&pk;
    u[0] = f2bf(v.x * inv); u[1] = f2bf(v.y * inv);
    u[2] = f2bf(v.z * inv); u[3] = f2bf(v.w * inv);
    *(i32x2*)(gpad + o) = pk;
}

// ---------------- weight transform to [chunk][tap][co][32ch] bf16, PLAIN ----------------
template <int CI>
__global__ __launch_bounds__(256) void k_wtrans(const float* __restrict__ w,
                                                ushort* __restrict__ wt) {
    int idx = blockIdx.x * 256 + threadIdx.x;
    if (idx >= 27 * 128 * CI) return;
    int chin = idx & 31;
    int co = (idx >> 5) & 127;
    int t3 = idx >> 12;
    int tap = t3 % 27;
    int chunk = t3 / 27;
    int ci = chunk * 32 + chin;
    wt[idx] = f2bf(w[((size_t)co * CI + ci) * 27 + tap]);
}

// ---------------- 3^3 conv: A-slab once/chunk + 3-page B ring, 1 barrier/tap ----------------
// block: 128 pos x 128 co, 256 thr / 4 waves, 2 blocks/CU (LDS = 64KB exactly).
// Per tap: vmcnt(2) [B(t) landed] -> s_barrier -> 16 MFMA (setprio) -> issue B(t+2)
// into page (t+2)%3. B swizzle (co>>1)&3 on BOTH stage & read: conflict-free.
template <int CI, bool PAD_OUT>
__global__ __launch_bounds__(256, 2) void k_conv(const ushort* __restrict__ inp,
                                                 const ushort* __restrict__ wt,
                                                 const float* __restrict__ bias,
                                                 ushort* __restrict__ outp,
                                                 float* __restrict__ gstats,
                                                 int layer) {
    constexpr int NCHUNK = CI / 32;
    __shared__ char lds[65536];            // slab 40960 (incl pad) + 3x8192 ring
    char* ring = lds + 40960;

    const int bid = blockIdx.x;
    const int wid = (bid & 7) * 128 + (bid >> 3);      // 1024 % 8 == 0: bijective
    const int yg = wid & 7;
    const int z0 = (wid >> 3) & 31;
    const int b = wid >> 8;
    const int y0 = yg * 4;
    const int tid = threadIdx.x;
    const int w = tid >> 6, l = tid & 63;
    const int lk = l >> 4, lr = l & 15;
    const int wr = w >> 1, wc = w & 1;

    const char* actb = (const char*)(inp + (size_t)b * PADV_ * CI);
    const char* wtb = (const char*)wt;

    int st_glb[10];
    #pragma unroll
    for (int j = 0; j < 10; ++j) {
        int c = j * 64 + (tid >> 2);
        if (c > 611) c = 611;
        int row = c / 34;
        int x = c - row * 34;
        int dz = row / 6, dy = row - dz * 6;
        int gz = z0 + dz, gy = y0 + dy;
        int lq = (tid & 3) ^ ((x >> 1) & 3);
        st_glb[j] = (gz * PPLANE_ + gy * 34 + x) * CI * 2 + lq * 16;
    }
    int bst[2];
    #pragma unroll
    for (int i = 0; i < 2; ++i) {
        int s = tid + i * 256;
        int q = s & 3, co = s >> 2;
        bst[i] = co * 64 + ((q ^ ((co >> 1) & 3)) << 4);
    }
    int aoff[4][3];
    #pragma unroll
    for (int i = 0; i < 4; ++i) {
        int pos = wr * 64 + i * 16 + lr;
        int ly = pos >> 5, x = pos & 31;
        #pragma unroll
        for (int fx = 0; fx < 3; ++fx) {
            int xc = x + fx;
            aoff[i][fx] = (ly * 34 + xc) * 64 + ((lk ^ ((xc >> 1) & 3)) << 4);
        }
    }
    int boff[4];
    #pragma unroll
    for (int n = 0; n < 4; ++n) {
        int co = wc * 64 + n * 16 + lr;
        boff[n] = co * 64 + ((lk ^ ((co >> 1) & 3)) << 4);
    }

    f32x4 acc[4][4];
    #pragma unroll
    for (int i = 0; i < 4; ++i)
        #pragma unroll
        for (int n = 0; n < 4; ++n)
            acc[i][n] = (f32x4){0.f, 0.f, 0.f, 0.f};

    #pragma unroll 1
    for (int chunk = 0; chunk < NCHUNK; ++chunk) {
        const char* srcb = actb + chunk * 64;
        const char* wch = wtb + (size_t)chunk * 27 * 8192;
        #pragma unroll
        for (int j = 0; j < 10; ++j)
            gl16(srcb + st_glb[j], lds + j * 4096 + w * 1024);
        #pragma unroll
        for (int i = 0; i < 2; ++i)
            gl16(wch + bst[i], ring + i * 4096 + w * 1024);
        #pragma unroll
        for (int i = 0; i < 2; ++i)
            gl16(wch + 8192 + bst[i], ring + 8192 + i * 4096 + w * 1024);

        #pragma unroll
        for (int t = 0; t < 27; ++t) {
            __builtin_amdgcn_sched_barrier(0);
            if (t == 26) {
                asm volatile("s_waitcnt vmcnt(0)" ::: "memory");
            } else {
                asm volatile("s_waitcnt vmcnt(2)" ::: "memory");
            }
            __builtin_amdgcn_sched_barrier(0);
            __builtin_amdgcn_s_barrier();
            __builtin_amdgcn_sched_barrier(0);
            const char* rp = ring + (t % 3) * 8192;
            const int fz = t / 9, r9v = t - fz * 9;
            const int fy = r9v / 3, fx = r9v - fy * 3;
            const int drow = (fz * 6 + fy) * 2176;
            bf16x8 af[4], bfr[4];
            #pragma unroll
            for (int i = 0; i < 4; ++i)
                af[i] = *(const bf16x8*)(lds + drow + aoff[i][fx]);
            #pragma unroll
            for (int n = 0; n < 4; ++n)
                bfr[n] = *(const bf16x8*)(rp + boff[n]);
            __builtin_amdgcn_s_setprio(1);
            #pragma unroll
            for (int i = 0; i < 4; ++i)
                #pragma unroll
                for (int n = 0; n < 4; ++n)
                    acc[i][n] = __builtin_amdgcn_mfma_f32_16x16x32_bf16(af[i], bfr[n], acc[i][n], 0, 0, 0);
            __builtin_amdgcn_s_setprio(0);
            __builtin_amdgcn_sched_barrier(0);
            if (t + 2 < 27) {
                const char* wp = wch + (size_t)(t + 2) * 8192;
                char* rw = ring + ((t + 2) % 3) * 8192;
                #pragma unroll
                for (int i = 0; i < 2; ++i)
                    gl16(wp + bst[i], rw + i * 4096 + w * 1024);
            }
            __builtin_amdgcn_sched_barrier(0);
        }
        __builtin_amdgcn_s_barrier();
        __builtin_amdgcn_sched_barrier(0);
    }

    // ---- epilogue: bias + fused GN stats + bf16 pack via LDS + coalesced dump ----
    ushort* outs = (ushort*)lds;
    float bb[4];
    #pragma unroll
    for (int n = 0; n < 4; ++n) bb[n] = bias[wc * 64 + n * 16 + lr];
    float sg[4] = {0.f, 0.f, 0.f, 0.f}, sq[4] = {0.f, 0.f, 0.f, 0.f};
    #pragma unroll
    for (int i = 0; i < 4; ++i) {
        int posb = wr * 64 + i * 16 + lk * 4;
        #pragma unroll
        for (int n = 0; n < 4; ++n) {
            int co = wc * 64 + n * 16 + lr;
            #pragma unroll
            for (int r = 0; r < 4; ++r) {
                float v = acc[i][n][r] + bb[n];
                sg[n] += v; sq[n] += v * v;
                outs[(posb + r) * 128 + co] = f2bf(v);
            }
        }
    }
    #pragma unroll
    for (int off = 1; off < 64; off <<= 1) {
        #pragma unroll
        for (int n = 0; n < 4; ++n) {
            sg[n] += __shfl_xor(sg[n], off);
            sq[n] += __shfl_xor(sq[n], off);
        }
    }
    if (l == 0) {
        int gbase = layer * 32 + b * 8 + wc * 4;
        #pragma unroll
        for (int n = 0; n < 4; ++n) {
            atomicAdd(&gstats[(gbase + n) * 2 + 0], sg[n]);
            atomicAdd(&gstats[(gbase + n) * 2 + 1], sq[n]);
        }
    }
    __syncthreads();
    for (int idx = tid; idx < 2048; idx += 256) {
        int pos = idx >> 4, c8 = idx & 15;
        int yy = y0 + (pos >> 5), xx = pos & 31;
        size_t g;
        if (PAD_OUT)
            g = ((size_t)b * PADV_ + (size_t)(z0 + 1) * PPLANE_ + (yy + 1) * 34 + (xx + 1)) * 128 + c8 * 8;
        else
            g = ((size_t)b * RRR_ + z0 * 1024 + yy * 32 + xx) * 128 + c8 * 8;
        *(i32x4*)(outp + g) = *((i32x4*)lds + idx);
    }
}

// ---------------- GN + SiLU apply (channels-last bf16, padded or flat) ----------------
template <bool PAD>
__global__ __launch_bounds__(256) void k_gn_apply(ushort* __restrict__ x,
                                                  const float* __restrict__ gstats,
                                                  const float* __restrict__ sc,
                                                  const float* __restrict__ bi,
                                                  int layer, float invc) {
    int idx = blockIdx.x * 256 + threadIdx.x;   // 4*32768*16
    int c8 = idx & 15;
    int vox = (idx >> 4) & 32767;
    int b = idx >> 19;
    size_t base;
    if (PAD) {
        int zz = vox >> 10, yy = (vox >> 5) & 31, xx = vox & 31;
        base = ((size_t)b * PADV_ + (size_t)(zz + 1) * PPLANE_ + (yy + 1) * 34 + (xx + 1)) * 128 + c8 * 8;
    } else {
        base = ((size_t)b * RRR_ + vox) * 128 + c8 * 8;
    }
    int g = c8 >> 1;
    float sum = gstats[(layer * 32 + b * 8 + g) * 2 + 0];
    float ssq = gstats[(layer * 32 + b * 8 + g) * 2 + 1];
    float mean = sum * invc;
    float var = ssq * invc - mean * mean;
    float rstd = rsqrtf(var + 1e-5f);
    i32x4 raw = *(i32x4*)(x + base);
    ushort* u = (ushort*)&raw;
    #pragma unroll
    for (int j = 0; j < 8; ++j) {
        int co = c8 * 8 + j;
        float v = bf2f(u[j]);
        v = (v - mean) * rstd * sc[co] + bi[co];
        v = v / (1.f + __expf(-v));
        u[j] = f2bf(v);
    }
    *(i32x4*)(x + base) = raw;
}

// ---------------- point MLP (1x1 conv) + fused GN stats, bf16 output ----------------
__global__ __launch_bounds__(256) void k_point_mlp(const float* __restrict__ feats,
                                                   const float* __restrict__ w,
                                                   const float* __restrict__ pb,
                                                   ushort* __restrict__ pbf,
                                                   float* __restrict__ gstats) {
    __shared__ float wl[64 * 132];
    __shared__ float sred[4][16];
    int tid = threadIdx.x;
    for (int i = tid; i < 128 * 64; i += 256) {
        int o = i >> 6, c = i & 63;
        wl[c * 132 + o] = w[i];
    }
    __syncthreads();
    int gid = blockIdx.x * 256 + tid;
    int b = gid >> 16, n = gid & (N_ - 1);
    const float* fb = feats + (size_t)b * 64 * N_ + n;
    float acc[128];
    #pragma unroll
    for (int o = 0; o < 128; ++o) acc[o] = 0.f;
    for (int c = 0; c < 64; ++c) {
        float f = fb[(size_t)c * N_];
        const float4* wr4 = (const float4*)&wl[c * 132];
        #pragma unroll
        for (int o4 = 0; o4 < 32; ++o4) {
            float4 wv = wr4[o4];
            acc[4 * o4 + 0] = fmaf(f, wv.x, acc[4 * o4 + 0]);
            acc[4 * o4 + 1] = fmaf(f, wv.y, acc[4 * o4 + 1]);
            acc[4 * o4 + 2] = fmaf(f, wv.z, acc[4 * o4 + 2]);
            acc[4 * o4 + 3] = fmaf(f, wv.w, acc[4 * o4 + 3]);
        }
    }
    ushort* ob = pbf + (size_t)b * 128 * N_ + n;
    float sg[8] = {0.f}, sq[8] = {0.f};
    #pragma unroll
    for (int o = 0; o < 128; ++o) {
        float v = acc[o] + pb[o];
        ob[(size_t)o * N_] = f2bf(v);
        sg[o >> 4] += v;
        sq[o >> 4] += v * v;
    }
    #pragma unroll
    for (int off = 1; off < 64; off <<= 1) {
        #pragma unroll
        for (int g = 0; g < 8; ++g) {
            sg[g] += __shfl_xor(sg[g], off);
            sq[g] += __shfl_xor(sq[g], off);
        }
    }
    int wv = tid >> 6, l = tid & 63;
    if (l == 0) {
        #pragma unroll
        for (int g = 0; g < 8; ++g) { sred[wv][g] = sg[g]; sred[wv][8 + g] = sq[g]; }
    }
    __syncthreads();
    if (tid < 16) {
        float v = sred[0][tid] + sred[1][tid] + sred[2][tid] + sred[3][tid];
        int g = tid & 7, part = tid >> 3;
        atomicAdd(&gstats[(64 + b * 8 + g) * 2 + part], v);
    }
}

// ---------------- devoxelize + point GN/SiLU + add; XCD-batch affinity ----------------
__global__ __launch_bounds__(256) void k_devox_final(const float* __restrict__ nc,
                                                     const ushort* __restrict__ ht,
                                                     const ushort* __restrict__ pbf,
                                                     const float* __restrict__ gstats,
                                                     const float* __restrict__ scale,
                                                     const float* __restrict__ bias,
                                                     float* __restrict__ out) {
    __shared__ float vp[64][129];
    __shared__ int sidx[64][8];
    __shared__ float swt[64][8];
    int tid = threadIdx.x;
    int blk = blockIdx.x;               // 4096; remap: XCD k serves only batch k/2
    int wid = (blk & 7) * 512 + (blk >> 3);   // 4096 % 8 == 0: bijective
    int b = wid >> 10;
    int n0 = (wid & 1023) * 64;
    if (tid < 64) {
        int n = n0 + tid;
        float f0 = nc[(size_t)b * 3 * N_ + n];
        float f1 = nc[((size_t)b * 3 + 1) * N_ + n];
        float f2 = nc[((size_t)b * 3 + 2) * N_ + n];
        float l0 = floorf(f0), l1 = floorf(f1), l2 = floorf(f2);
        float r0 = f0 - l0, r1 = f1 - l1, r2 = f2 - l2;
        int i0 = (int)l0, i1 = (int)l1, i2 = (int)l2;
        int h0 = min(i0 + 1, 31), h1 = min(i1 + 1, 31), h2 = min(i2 + 1, 31);
        #pragma unroll
        for (int k = 0; k < 8; ++k) {
            int dx = (k >> 2) & 1, dy = (k >> 1) & 1, dz = k & 1;
            int ix = dx ? h0 : i0, iy = dy ? h1 : i1, iz = dz ? h2 : i2;
            float w = (dx ? r0 : 1.f - r0) * (dy ? r1 : 1.f - r1) * (dz ? r2 : 1.f - r2);
            sidx[tid][k] = (ix * 32 + iy) * 32 + iz;
            swt[tid][k] = w;
        }
    }
    __syncthreads();
    const ushort* hb = ht + (size_t)b * RRR_ * 128;
    for (int t = tid; t < 64 * 16; t += 256) {
        int c8 = t & 15, pt = t >> 4;
        float a[8] = {0.f, 0.f, 0.f, 0.f, 0.f, 0.f, 0.f, 0.f};
        #pragma unroll
        for (int k = 0; k < 8; ++k) {
            i32x4 raw = *(const i32x4*)(hb + (size_t)sidx[pt][k] * 128 + c8 * 8);
            ushort* u = (ushort*)&raw;
            float wk = swt[pt][k];
            #pragma unroll
            for (int j = 0; j < 8; ++j)
                a[j] = fmaf(wk, bf2f(u[j]), a[j]);
        }
        #pragma unroll
        for (int j = 0; j < 8; ++j)
            vp[pt][c8 * 8 + j] = a[j];
    }
    __syncthreads();
    const float invc = 1.0f / (16.0f * (float)N_);
    for (int t = tid; t < 64 * 128; t += 256) {
        int nl = t & 63;
        int c = t >> 6;
        int g = c >> 4;
        float sum = gstats[(64 + b * 8 + g) * 2 + 0];
        float ssq = gstats[(64 + b * 8 + g) * 2 + 1];
        float mean = sum * invc;
        float var = ssq * invc - mean * mean;
        float rstd = rsqrtf(var + 1e-5f);
        size_t o = ((size_t)(b * 128 + c)) * N_ + n0 + nl;
        float v = (bf2f(pbf[o]) - mean) * rstd * scale[c] + bias[c];
        v = v / (1.f + __expf(-v));
        out[o] = v + vp[nl][c];
    }
}

extern "C" void kernel_launch(void* const* d_in, const int* in_sizes, int n_in,
                              void* d_out, int out_size, void* d_ws, size_t ws_size,
                              hipStream_t stream) {
    const float* coords   = (const float*)d_in[0];
    const float* features = (const float*)d_in[1];
    const float* conv1_w  = (const float*)d_in[2];
    const float* conv1_b  = (const float*)d_in[3];
    const float* gn1_s    = (const float*)d_in[4];
    const float* gn1_b    = (const float*)d_in[5];
    const float* conv2_w  = (const float*)d_in[6];
    const float* conv2_b  = (const float*)d_in[7];
    const float* gn2_s    = (const float*)d_in[8];
    const float* gn2_b    = (const float*)d_in[9];
    const float* point_w  = (const float*)d_in[10];
    const float* point_b  = (const float*)d_in[11];
    const float* pgn_s    = (const float*)d_in[12];
    const float* pgn_b    = (const float*)d_in[13];
    float* out = (float*)d_out;
    float* ws = (float*)d_ws;

    float*  nc     = ws + OFF_NC;
    int*    vidx   = (int*)(ws + OFF_VIDX);
    ushort* wt1    = (ushort*)(ws + OFF_WT1);
    ushort* wt2    = (ushort*)(ws + OFF_WT2);
    ushort* c2out  = (ushort*)(ws + OFF_C2OUT);
    float*  cnt    = ws + OFF_CNT;
    float*  gsum   = ws + OFF_GSUM;
    ushort* gpad   = (ushort*)(ws + OFF_GPAD);
    ushort* act1   = (ushort*)(ws + OFF_ACT1);
    float*  gstats = ws + OFF_GSTATS;
    float*  bstats = ws + OFF_BSTATS;
    ushort* pbf    = (ushort*)(ws + OFF_PBF);   // reuses gsum/gpad/act1 after conv2

    const float invc = 1.0f / (float)(RRR_ * 16);

    // zero only what must be zero: atomic accumulators + stats + buffer halos
    // (gpad/act1 interiors are fully overwritten by gridmean/conv1 every call)
    hipMemsetAsync(cnt, 0, MEMSET1_FLOATS * sizeof(float), stream);
    hipMemsetAsync(gstats, 0, (192 + 16) * sizeof(float), stream);
    k_zero_halo<8><<<(B_ * PADV_ * 8 + 255) / 256, 256, 0, stream>>>(gpad);
    k_zero_halo<16><<<(B_ * PADV_ * 16 + 255) / 256, 256, 0, stream>>>(act1);

    k_coord_sum<<<dim3(64, B_), 256, 0, stream>>>(coords, bstats);
    k_coord_max<<<dim3(64, B_), 256, 0, stream>>>(coords, bstats);
    k_point_prep<<<B_ * N_ / 256, 256, 0, stream>>>(coords, bstats, nc, vidx, cnt);
    k_scatter_cl<<<dim3(N_ / 128, B_), 256, 0, stream>>>(features, vidx, gsum);
    k_gridmean_cl<<<B_ * RRR_ * 16 / 256, 256, 0, stream>>>(gsum, cnt, gpad);

    k_wtrans<64><<<(27 * 128 * 64 + 255) / 256, 256, 0, stream>>>(conv1_w, wt1);
    k_wtrans<128><<<(27 * 128 * 128 + 255) / 256, 256, 0, stream>>>(conv2_w, wt2);

    k_conv<64, true><<<1024, 256, 0, stream>>>(gpad, wt1, conv1_b, act1, gstats, 0);
    k_gn_apply<true><<<B_ * RRR_ * 16 / 256, 256, 0, stream>>>(act1, gstats, gn1_s, gn1_b, 0, invc);

    k_conv<128, false><<<1024, 256, 0, stream>>>(act1, wt2, conv2_b, c2out, gstats, 1);
    k_gn_apply<false><<<B_ * RRR_ * 16 / 256, 256, 0, stream>>>(c2out, gstats, gn2_s, gn2_b, 1, invc);

    // point branch AFTER conv2: pbf overlaps gsum/gpad/act1 (dead now)
    k_point_mlp<<<B_ * N_ / 256, 256, 0, stream>>>(features, point_w, point_b, pbf, gstats);
    k_devox_final<<<B_ * N_ / 64, 256, 0, stream>>>(nc, c2out, pbf, gstats, pgn_s, pgn_b, out);
}